// Round 6
// baseline (415.039 us; speedup 1.0000x reference)
//
#include <hip/hip_runtime.h>
#include <hip/hip_bf16.h>

#define N_ROWS 131072
#define DIM 256
#define K_CODES 1024
#define BLK_ROWS 128        // 4 waves x 32 rows; 2 blocks/CU (load-bearing: r3/r4 regressions)
#define NCHUNK 32           // 32 codes per chunk
#define FRAG_SH 512         // shorts per fragment (64 lanes x 8 bf16)
#define CHUNK_SH (32 * FRAG_SH)   // bg layout: 32 frags/chunk: [0..16)=GEMM1 A, [16..32)=GEMM2 B
#define ACHUNK_SH (16 * FRAG_SH)  // 16 KB half-chunk (A-frags or B-frags)

typedef __attribute__((ext_vector_type(8))) short bf16x8;
typedef __attribute__((ext_vector_type(16))) float f32x16;

__device__ __forceinline__ short f2bf(float x) {
    unsigned u = __float_as_uint(x);
    u += 0x7fff + ((u >> 16) & 1);   // RNE
    return (short)(u >> 16);
}
// NOTE (r5 lesson, = guide m240): do NOT replace f2bf with inline-asm
// v_cvt_pk_bf16_f32 — each asm is a scheduling fence; VALUBusy dropped but
// dur +11% (239->266 us). Manual f2bf schedules freely.

typedef const __attribute__((address_space(1))) unsigned int* gas1_t;
typedef __attribute__((address_space(3))) unsigned int* las3_t;
__device__ __forceinline__ void gload16(const short* g, short* l) {
    // per-lane global addr (contiguous 16B/lane); wave-uniform LDS base + lane*16
    __builtin_amdgcn_global_load_lds((gas1_t)(const void*)g, (las3_t)(void*)l, 16, 0, 0);
}

// ---------------- prep: codebook -> fragment-order bf16 (one block per 32-code chunk)
__global__ void prep_kernel(const float* __restrict__ cb,
                            short* __restrict__ bg) {
    __shared__ __align__(16) float tile[32 * 264];   // [code][d] fp32, stride 264
    __shared__ float en2s[32];
    const int tid = threadIdx.x;
    const int w = tid >> 6, l = tid & 63, hf = l >> 5, c31 = l & 31;
    const int ch = blockIdx.x, cb0 = ch * 32;

#pragma unroll
    for (int it = 0; it < 8; ++it) {
        int idx = it * 256 + tid;          // float4 index
        int r = idx >> 6, c = (idx & 63) * 4;
        *(float4*)&tile[r * 264 + c] = *(const float4*)&cb[(size_t)(cb0 + r) * DIM + c];
    }
    __syncthreads();

    {   // en2[c] = exp(-||e_c||^2), 8 threads per code
        int c = tid >> 3, part = tid & 7;
        float s = 0.f;
#pragma unroll
        for (int j = 0; j < 32; ++j) {
            float v = tile[c * 264 + part * 32 + j];
            s += v * v;
        }
        s += __shfl_xor(s, 1, 64);
        s += __shfl_xor(s, 2, 64);
        s += __shfl_xor(s, 4, 64);
        if (part == 0) en2s[c] = __expf(-s);
    }
    __syncthreads();

    // GEMM1 A-frags (f = t = 0..15): lane holds E[cb0 + c31][t*16 + hf*8 + j]
#pragma unroll
    for (int i = 0; i < 4; ++i) {
        int f = i * 4 + w;
        const float* src = &tile[c31 * 264 + f * 16 + hf * 8];
        float4 v0 = *(const float4*)src;
        float4 v1 = *(const float4*)(src + 4);
        bf16x8 v;
        v[0] = f2bf(v0.x); v[1] = f2bf(v0.y); v[2] = f2bf(v0.z); v[3] = f2bf(v0.w);
        v[4] = f2bf(v1.x); v[5] = f2bf(v1.y); v[6] = f2bf(v1.z); v[7] = f2bf(v1.w);
        *(bf16x8*)&bg[ch * CHUNK_SH + f * FRAG_SH + l * 8] = v;
    }
    // GEMM2 B-frags (f = 16 + n2*2 + t2), en2-folded, kappa code order:
    // slot (hf, j) holds code (t2*2 + (j>>2))*8 + 4*hf + (j&3), matching P's A-register order
#pragma unroll
    for (int i = 0; i < 4; ++i) {
        int g = i * 4 + w;
        int n2 = g >> 1, t2 = g & 1;
        int d = n2 * 32 + c31;
        bf16x8 v;
#pragma unroll
        for (int j = 0; j < 8; ++j) {
            int c2 = (t2 * 2 + (j >> 2)) * 8 + 4 * hf + (j & 3);
            v[j] = f2bf(tile[c2 * 264 + d] * en2s[c2]);
        }
        *(bf16x8*)&bg[ch * CHUNK_SH + (16 + g) * FRAG_SH + l * 8] = v;
    }
}

// ---------------- main fused kernel ----------------
// Structure locked by measurement (do not revisit):
//  - 2 x 4-wave blocks/CU with per-chunk __syncthreads: cross-block wave overlap
//    carries the kernel (8-wave/counted-vmcnt variant: -24%; r3)
//  - ALL MFMA operands via LDS: L2-direct A-frags serialize on load latency at
//    the 256-reg/wave cap (-85%; r4)
//  - n2-outer cached stores: row-outer +65MB WRITE (r1), nontemporal +68MB (r3)
//  - manual f2bf, not asm cvt_pk: asm fences serialize phases (-11%; r5)
//
// r6 schedule rotation (software pipeline across chunks, same LDS/barriers):
//   slot ch: [stage A(ch+2)->Ab[ch&1], B(ch+1)->Bb[(ch+1)&1];
//             SM(ch) (register-only, issues immediately post-barrier);
//             GEMM2(ch) (8 indep chains) 1:1-interleaved with GEMM1(ch+1)
//             (16-dep chain gets latency cover); __syncthreads]
// Race audit (each overwrite is >= 1 barrier after its last read):
//   write Ab[ch&1]=A(ch+2): last read = GEMM1(ch) in slot ch-1  -> barrier(ch-1) OK
//   write Bb[(ch+1)&1]=B(ch+1): last read = GEMM2(ch-1) in slot ch-1 -> OK
//   read Ab[(ch+1)&1]=A(ch+1): staged slot ch-1 (or prologue), drained by
//     the vmcnt(0) inside barrier(ch-1) -> OK; read Bb[ch&1]=B(ch) same -> OK
__global__ __launch_bounds__(256, 2)
void svq_kernel(const float* __restrict__ z,
                const short* __restrict__ bg,
                float* __restrict__ out,
                float* __restrict__ loss) {
    __shared__ __align__(16) short lds_A[2 * ACHUNK_SH];  // 2 x 16 KB, GEMM1 A-frags
    __shared__ __align__(16) short lds_B[2 * ACHUNK_SH];  // 2 x 16 KB, GEMM2 B-frags

    const int tid = threadIdx.x;
    const int w = tid >> 6, l = tid & 63, hf = l >> 5, c31 = l & 31;
    const int rowbase = blockIdx.x * BLK_ROWS + w * 32;

    // z fragments: lane holds z[rowbase + c31][t*16 + hf*8 + j].
    // Same register layout serves as MFMA B-operand (B[k=d][n=row]) for GEMM1.
    bf16x8 za[16];
    float sz2 = 0.f;   // exact fp32 sum of z^2 over this lane's 128 elements
    {
        const float* zr = z + (size_t)(rowbase + c31) * DIM + hf * 8;
#pragma unroll
        for (int t = 0; t < 16; ++t) {
            float4 v0 = *(const float4*)(zr + t * 16);
            float4 v1 = *(const float4*)(zr + t * 16 + 4);
            sz2 += v0.x*v0.x + v0.y*v0.y + v0.z*v0.z + v0.w*v0.w
                 + v1.x*v1.x + v1.y*v1.y + v1.z*v1.z + v1.w*v1.w;
            bf16x8 a;
            a[0] = f2bf(v0.x); a[1] = f2bf(v0.y); a[2] = f2bf(v0.z); a[3] = f2bf(v0.w);
            a[4] = f2bf(v1.x); a[5] = f2bf(v1.y); a[6] = f2bf(v1.z); a[7] = f2bf(v1.w);
            za[t] = a;
        }
    }

    f32x16 o[8];
#pragma unroll
    for (int i = 0; i < 8; ++i)
        o[i] = (f32x16){0.f,0.f,0.f,0.f,0.f,0.f,0.f,0.f,0.f,0.f,0.f,0.f,0.f,0.f,0.f,0.f};
    float rs0 = 0.f, rs1 = 0.f;   // sum of p over this lane's codes (two partials)
    float q0 = 0.f,  q1 = 0.f;    // sum of p*s -> z_soft . z (two partials)

    // prologue: stage A(0)->Ab0, B(0)->Bb0, A(1)->Ab1; sync; GEMM1(0); sync
    {
        const short* sgA0 = bg + l * 8;
        const short* sgB0 = bg + 16 * FRAG_SH + l * 8;
        const short* sgA1 = bg + CHUNK_SH + l * 8;
#pragma unroll
        for (int i = 0; i < 4; ++i) {
            int f = i * 4 + w;
            gload16(sgA0 + f * FRAG_SH, &lds_A[f * FRAG_SH]);
        }
#pragma unroll
        for (int i = 0; i < 4; ++i) {
            int f = i * 4 + w;
            gload16(sgB0 + f * FRAG_SH, &lds_B[f * FRAG_SH]);
            gload16(sgA1 + f * FRAG_SH, &lds_A[ACHUNK_SH + f * FRAG_SH]);
        }
    }
    __syncthreads();

    f32x16 s = (f32x16){0.f,0.f,0.f,0.f,0.f,0.f,0.f,0.f,0.f,0.f,0.f,0.f,0.f,0.f,0.f,0.f};
    {
        const short* la = &lds_A[l * 8];
#pragma unroll
        for (int t = 0; t < 16; ++t) {
            bf16x8 a = *(const bf16x8*)(la + t * FRAG_SH);
            s = __builtin_amdgcn_mfma_f32_32x32x16_bf16(a, za[t], s, 0, 0, 0);
        }
    }
    __syncthreads();   // separates GEMM1(0) reads of Ab0 from slot-0's A(2) stage

    for (int ch = 0; ch < NCHUNK - 1; ++ch) {
        // stage A(ch+2) and B(ch+1) (buffers free per race audit above)
        if (ch + 2 < NCHUNK) {
            const short* sg = bg + (ch + 2) * CHUNK_SH + l * 8;
            short* lb = &lds_A[(ch & 1) * ACHUNK_SH];
#pragma unroll
            for (int i = 0; i < 4; ++i) {
                int f = i * 4 + w;
                gload16(sg + f * FRAG_SH, lb + f * FRAG_SH);
            }
        }
        {
            const short* sg = bg + (ch + 1) * CHUNK_SH + 16 * FRAG_SH + l * 8;
            short* lb = &lds_B[((ch + 1) & 1) * ACHUNK_SH];
#pragma unroll
            for (int i = 0; i < 4; ++i) {
                int f = i * 4 + w;
                gload16(sg + f * FRAG_SH, lb + f * FRAG_SH);
            }
        }

        const short* lbB = &lds_B[(ch & 1) * ACHUNK_SH + l * 8];
        const short* lbA = &lds_A[((ch + 1) & 1) * ACHUNK_SH + l * 8];

        f32x16 sn = (f32x16){0.f,0.f,0.f,0.f,0.f,0.f,0.f,0.f,0.f,0.f,0.f,0.f,0.f,0.f,0.f,0.f};

        // softmax half 1 (regs 0..7 -> a20): register-only, issues right after
        // the barrier with no LDS dependency
        bf16x8 a20;
#pragma unroll
        for (int reg = 0; reg < 8; ++reg) {
            float sv = s[reg];
            float p = exp2f(sv * 2.8853900818f);   // exp(2 z.e)
            if (reg & 1) { rs1 += p; q1 += p * sv; }
            else         { rs0 += p; q0 += p * sv; }
            a20[reg] = f2bf(p);
        }
        // 8 x { GEMM2(ch) a20-op ; GEMM1(ch+1) dep-chain op }
#pragma unroll
        for (int n2 = 0; n2 < 8; ++n2) {
            bf16x8 b0 = *(const bf16x8*)(lbB + (n2 * 2) * FRAG_SH);
            o[n2] = __builtin_amdgcn_mfma_f32_32x32x16_bf16(a20, b0, o[n2], 0, 0, 0);
            bf16x8 a = *(const bf16x8*)(lbA + n2 * FRAG_SH);
            sn = __builtin_amdgcn_mfma_f32_32x32x16_bf16(a, za[n2], sn, 0, 0, 0);
        }

        // softmax half 2 (regs 8..15 -> a21)
        bf16x8 a21;
#pragma unroll
        for (int reg = 8; reg < 16; ++reg) {
            float sv = s[reg];
            float p = exp2f(sv * 2.8853900818f);
            if (reg & 1) { rs1 += p; q1 += p * sv; }
            else         { rs0 += p; q0 += p * sv; }
            a21[reg - 8] = f2bf(p);
        }
#pragma unroll
        for (int n2 = 0; n2 < 8; ++n2) {
            bf16x8 b1 = *(const bf16x8*)(lbB + (n2 * 2 + 1) * FRAG_SH);
            o[n2] = __builtin_amdgcn_mfma_f32_32x32x16_bf16(a21, b1, o[n2], 0, 0, 0);
            bf16x8 a = *(const bf16x8*)(lbA + (8 + n2) * FRAG_SH);
            sn = __builtin_amdgcn_mfma_f32_32x32x16_bf16(a, za[8 + n2], sn, 0, 0, 0);
        }

        s = sn;
        __syncthreads();
    }

    // peeled last slot (ch = NCHUNK-1): SM + GEMM2 only, no staging, no barrier
    {
        const short* lbB = &lds_B[((NCHUNK - 1) & 1) * ACHUNK_SH + l * 8];
        bf16x8 a20;
#pragma unroll
        for (int reg = 0; reg < 8; ++reg) {
            float sv = s[reg];
            float p = exp2f(sv * 2.8853900818f);
            if (reg & 1) { rs1 += p; q1 += p * sv; }
            else         { rs0 += p; q0 += p * sv; }
            a20[reg] = f2bf(p);
        }
#pragma unroll
        for (int n2 = 0; n2 < 8; ++n2) {
            bf16x8 b0 = *(const bf16x8*)(lbB + (n2 * 2) * FRAG_SH);
            o[n2] = __builtin_amdgcn_mfma_f32_32x32x16_bf16(a20, b0, o[n2], 0, 0, 0);
        }
        bf16x8 a21;
#pragma unroll
        for (int reg = 8; reg < 16; ++reg) {
            float sv = s[reg];
            float p = exp2f(sv * 2.8853900818f);
            if (reg & 1) { rs1 += p; q1 += p * sv; }
            else         { rs0 += p; q0 += p * sv; }
            a21[reg - 8] = f2bf(p);
        }
#pragma unroll
        for (int n2 = 0; n2 < 8; ++n2) {
            bf16x8 b1 = *(const bf16x8*)(lbB + (n2 * 2 + 1) * FRAG_SH);
            o[n2] = __builtin_amdgcn_mfma_f32_32x32x16_bf16(a21, b1, o[n2], 0, 0, 0);
        }
    }

    // combine the two half-dim/half-code lanes of each row
    float rs = rs0 + rs1, q = q0 + q1;
    float rs_t = rs + __shfl_xor(rs, 32, 64);
    float q_t  = q  + __shfl_xor(q, 32, 64);
    float inv  = 1.f / rs_t;

    // broadcast inv to the C-layout rows this lane will store
    float invr[16];
#pragma unroll
    for (int reg = 0; reg < 16; ++reg) {
        int r = (reg & 3) + 8 * (reg >> 2) + 4 * hf;
        invr[reg] = __shfl(inv, r, 64);
    }

    // epilogue: normalize, store, accumulate loss terms.
    // n2-outer + plain cached stores is measured-best. Do not "fix" this again.
    float zs2 = 0.f;
    const size_t ob = (size_t)rowbase * DIM;
#pragma unroll
    for (int n2 = 0; n2 < 8; ++n2) {
#pragma unroll
        for (int reg = 0; reg < 16; ++reg) {
            int r = (reg & 3) + 8 * (reg >> 2) + 4 * hf;
            float v = o[n2][reg] * invr[reg];
            out[ob + (size_t)r * DIM + n2 * 32 + c31] = v;
            zs2 += v * v;
        }
    }

    // loss = mean(z^2) - 2*mean(zs.z) + mean(zs^2); zs.z per row = q_t * inv
    float lacc = sz2 + zs2;
    if (hf == 0) lacc -= 2.f * q_t * inv;
#pragma unroll
    for (int off = 32; off > 0; off >>= 1) lacc += __shfl_xor(lacc, off, 64);
    if (l == 0) atomicAdd(loss, lacc * (1.f / ((float)N_ROWS * (float)DIM)));
}

extern "C" void kernel_launch(void* const* d_in, const int* in_sizes, int n_in,
                              void* d_out, int out_size, void* d_ws, size_t ws_size,
                              hipStream_t stream) {
    const float* z = (const float*)d_in[0];
    const float* cb = (const float*)d_in[1];
    float* out = (float*)d_out;

    short* bg = (short*)d_ws;    // 32 chunks * 16384 shorts = 1 MB

    float* loss = out + (size_t)N_ROWS * DIM;
    hipMemsetAsync((void*)loss, 0, sizeof(float), stream);

    prep_kernel<<<dim3(NCHUNK), dim3(256), 0, stream>>>(cb, bg);
    svq_kernel<<<dim3(N_ROWS / BLK_ROWS), dim3(256), 0, stream>>>(
        z, bg, out, loss);
}

// Round 9
// 402.974 us; speedup vs baseline: 1.0299x; 1.0299x over previous
//
#include <hip/hip_runtime.h>
#include <hip/hip_bf16.h>

#define N_ROWS 131072
#define DIM 256
#define K_CODES 1024
#define BLK_ROWS 128        // 4 waves x 32 rows; 2 blocks/CU (load-bearing: r3/r4 regressions)
#define NCHUNK 32           // 32 codes per chunk
#define FRAG_SH 512         // shorts per fragment (64 lanes x 8 bf16)
#define CHUNK_SH (32 * FRAG_SH)   // 32 frags/chunk: [0..16)=GEMM1 A, [16..32)=GEMM2 B

typedef __attribute__((ext_vector_type(8))) short bf16x8;
typedef __attribute__((ext_vector_type(16))) float f32x16;

__device__ __forceinline__ short f2bf(float x) {
    unsigned u = __float_as_uint(x);
    u += 0x7fff + ((u >> 16) & 1);   // RNE
    return (short)(u >> 16);
}
// NOTE (r5 lesson, = guide m240): do NOT replace f2bf with inline-asm
// v_cvt_pk_bf16_f32 — each asm is a scheduling fence; dur +11%.

typedef const __attribute__((address_space(1))) unsigned int* gas1_t;
typedef __attribute__((address_space(3))) unsigned int* las3_t;
__device__ __forceinline__ void gload16(const short* g, short* l) {
    // per-lane global addr (contiguous 16B/lane); wave-uniform LDS base + lane*16
    __builtin_amdgcn_global_load_lds((gas1_t)(const void*)g, (las3_t)(void*)l, 16, 0, 0);
}

// ---------------- prep: codebook -> fragment-order bf16 (one block per 32-code chunk)
__global__ void prep_kernel(const float* __restrict__ cb,
                            short* __restrict__ bg) {
    __shared__ __align__(16) float tile[32 * 264];   // [code][d] fp32, stride 264
    __shared__ float en2s[32];
    const int tid = threadIdx.x;
    const int w = tid >> 6, l = tid & 63, hf = l >> 5, c31 = l & 31;
    const int ch = blockIdx.x, cb0 = ch * 32;

#pragma unroll
    for (int it = 0; it < 8; ++it) {
        int idx = it * 256 + tid;          // float4 index
        int r = idx >> 6, c = (idx & 63) * 4;
        *(float4*)&tile[r * 264 + c] = *(const float4*)&cb[(size_t)(cb0 + r) * DIM + c];
    }
    __syncthreads();

    {   // en2[c] = exp(-||e_c||^2), 8 threads per code
        int c = tid >> 3, part = tid & 7;
        float s = 0.f;
#pragma unroll
        for (int j = 0; j < 32; ++j) {
            float v = tile[c * 264 + part * 32 + j];
            s += v * v;
        }
        s += __shfl_xor(s, 1, 64);
        s += __shfl_xor(s, 2, 64);
        s += __shfl_xor(s, 4, 64);
        if (part == 0) en2s[c] = __expf(-s);
    }
    __syncthreads();

    // GEMM1 A-frags (f = t = 0..15): lane holds E[cb0 + c31][t*16 + hf*8 + j]
#pragma unroll
    for (int i = 0; i < 4; ++i) {
        int f = i * 4 + w;
        const float* src = &tile[c31 * 264 + f * 16 + hf * 8];
        float4 v0 = *(const float4*)src;
        float4 v1 = *(const float4*)(src + 4);
        bf16x8 v;
        v[0] = f2bf(v0.x); v[1] = f2bf(v0.y); v[2] = f2bf(v0.z); v[3] = f2bf(v0.w);
        v[4] = f2bf(v1.x); v[5] = f2bf(v1.y); v[6] = f2bf(v1.z); v[7] = f2bf(v1.w);
        *(bf16x8*)&bg[ch * CHUNK_SH + f * FRAG_SH + l * 8] = v;
    }
    // GEMM2 B-frags (f = 16 + n2*2 + t2), en2-folded, kappa code order:
    // slot (hf, j) holds code (t2*2 + (j>>2))*8 + 4*hf + (j&3), matching P's A-register order
#pragma unroll
    for (int i = 0; i < 4; ++i) {
        int g = i * 4 + w;
        int n2 = g >> 1, t2 = g & 1;
        int d = n2 * 32 + c31;
        bf16x8 v;
#pragma unroll
        for (int j = 0; j < 8; ++j) {
            int c2 = (t2 * 2 + (j >> 2)) * 8 + 4 * hf + (j & 3);
            v[j] = f2bf(tile[c2 * 264 + d] * en2s[c2]);
        }
        *(bf16x8*)&bg[ch * CHUNK_SH + (16 + g) * FRAG_SH + l * 8] = v;
    }
}

// ---------------- main fused kernel ----------------
// Structure locked by measurement (do not revisit):
//  - 2 x 4-wave blocks/CU with per-chunk __syncthreads: cross-block wave overlap
//    carries the kernel (8-wave/counted-vmcnt: -24% r3; cross-chunk rotation: -24% r6)
//  - ALL MFMA operands via LDS: L2-direct A-frags serialize on load latency at
//    the register cap (-85%; r4)
//  - n2-outer cached stores: row-outer +65MB WRITE (r1), nontemporal +68MB (r3)
//  - manual f2bf, not asm cvt_pk: asm fences serialize phases (-11%; r5)
// r7 change (r6 proved +16 AGPR keeps occupancy): GEMM1 accumulates into TWO
// interleaved 8-deep chains (sA/sB) instead of one 16-deep dependent chain,
// halving the MFMA dep-latency serialization; summed during softmax reads.
__global__ __launch_bounds__(256, 2)
void svq_kernel(const float* __restrict__ z,
                const short* __restrict__ bg,
                float* __restrict__ out,
                float* __restrict__ loss) {
    __shared__ __align__(16) short lds_b[2 * CHUNK_SH];  // 2 x 32 KB double buffer

    const int tid = threadIdx.x;
    const int w = tid >> 6, l = tid & 63, hf = l >> 5, c31 = l & 31;
    const int rowbase = blockIdx.x * BLK_ROWS + w * 32;

    // z fragments: lane holds z[rowbase + c31][t*16 + hf*8 + j].
    // Same register layout serves as MFMA B-operand (B[k=d][n=row]) for GEMM1.
    bf16x8 za[16];
    float sz2 = 0.f;   // exact fp32 sum of z^2 over this lane's 128 elements
    {
        const float* zr = z + (size_t)(rowbase + c31) * DIM + hf * 8;
#pragma unroll
        for (int t = 0; t < 16; ++t) {
            float4 v0 = *(const float4*)(zr + t * 16);
            float4 v1 = *(const float4*)(zr + t * 16 + 4);
            sz2 += v0.x*v0.x + v0.y*v0.y + v0.z*v0.z + v0.w*v0.w
                 + v1.x*v1.x + v1.y*v1.y + v1.z*v1.z + v1.w*v1.w;
            bf16x8 a;
            a[0] = f2bf(v0.x); a[1] = f2bf(v0.y); a[2] = f2bf(v0.z); a[3] = f2bf(v0.w);
            a[4] = f2bf(v1.x); a[5] = f2bf(v1.y); a[6] = f2bf(v1.z); a[7] = f2bf(v1.w);
            za[t] = a;
        }
    }

    f32x16 o[8];
#pragma unroll
    for (int i = 0; i < 8; ++i)
        o[i] = (f32x16){0.f,0.f,0.f,0.f,0.f,0.f,0.f,0.f,0.f,0.f,0.f,0.f,0.f,0.f,0.f,0.f};
    float rs0 = 0.f, rs1 = 0.f;   // sum of p over this lane's codes (two partials)
    float q0 = 0.f,  q1 = 0.f;    // sum of p*s -> z_soft . z (two partials)

    // prologue: stage chunk 0 into buffer 0
    {
        const short* sg = bg + l * 8;
#pragma unroll
        for (int i = 0; i < 8; ++i) {
            int f = i * 4 + w;
            gload16(sg + f * FRAG_SH, &lds_b[f * FRAG_SH]);
        }
    }

    for (int ch = 0; ch < NCHUNK; ++ch) {
        // drains chunk-ch staging (which had all of compute(ch-1) to overlap)
        // and makes buffer (ch+1)&1 safe to overwrite
        __syncthreads();
        if (ch + 1 < NCHUNK) {
            const short* sg = bg + (ch + 1) * CHUNK_SH + l * 8;
            short* lbase = &lds_b[((ch + 1) & 1) * CHUNK_SH];
#pragma unroll
            for (int i = 0; i < 8; ++i) {
                int f = i * 4 + w;
                gload16(sg + f * FRAG_SH, lbase + f * FRAG_SH);
            }
        }

        const short* lb = &lds_b[(ch & 1) * CHUNK_SH + l * 8];

        // GEMM1 (transposed): S^T[32 codes x 32 rows] = E . Z^T
        // Two interleaved 8-deep accumulator chains (dep-latency halved vs 16-deep).
        f32x16 sA = (f32x16){0.f,0.f,0.f,0.f,0.f,0.f,0.f,0.f,0.f,0.f,0.f,0.f,0.f,0.f,0.f,0.f};
        f32x16 sB = (f32x16){0.f,0.f,0.f,0.f,0.f,0.f,0.f,0.f,0.f,0.f,0.f,0.f,0.f,0.f,0.f,0.f};
#pragma unroll
        for (int t = 0; t < 8; ++t) {
            bf16x8 a0 = *(const bf16x8*)(lb + t * FRAG_SH);
            sA = __builtin_amdgcn_mfma_f32_32x32x16_bf16(a0, za[t], sA, 0, 0, 0);
            bf16x8 a1 = *(const bf16x8*)(lb + (8 + t) * FRAG_SH);
            sB = __builtin_amdgcn_mfma_f32_32x32x16_bf16(a1, za[8 + t], sB, 0, 0, 0);
        }

        // softmax half 1 (regs 0..7 -> a20), then ISSUE its 8 GEMM2 MFMAs
        // immediately so they drain in the matrix pipe while the wave computes
        // half 2 on the VALU (MFMA issue is non-blocking for the wave).
        bf16x8 a20;
#pragma unroll
        for (int reg = 0; reg < 8; ++reg) {
            float sv = sA[reg] + sB[reg];
            float p = exp2f(sv * 2.8853900818f);   // exp(2 z.e)
            if (reg & 1) { rs1 += p; q1 += p * sv; }
            else         { rs0 += p; q0 += p * sv; }
            a20[reg] = f2bf(p);
        }
#pragma unroll
        for (int n2 = 0; n2 < 8; ++n2) {
            bf16x8 b0 = *(const bf16x8*)(lb + (16 + n2 * 2) * FRAG_SH);
            o[n2] = __builtin_amdgcn_mfma_f32_32x32x16_bf16(a20, b0, o[n2], 0, 0, 0);
        }

        // softmax half 2 (regs 8..15 -> a21), then its 8 GEMM2 MFMAs
        bf16x8 a21;
#pragma unroll
        for (int reg = 8; reg < 16; ++reg) {
            float sv = sA[reg] + sB[reg];
            float p = exp2f(sv * 2.8853900818f);
            if (reg & 1) { rs1 += p; q1 += p * sv; }
            else         { rs0 += p; q0 += p * sv; }
            a21[reg - 8] = f2bf(p);
        }
#pragma unroll
        for (int n2 = 0; n2 < 8; ++n2) {
            bf16x8 b1 = *(const bf16x8*)(lb + (16 + n2 * 2 + 1) * FRAG_SH);
            o[n2] = __builtin_amdgcn_mfma_f32_32x32x16_bf16(a21, b1, o[n2], 0, 0, 0);
        }
    }

    // combine the two half-dim/half-code lanes of each row
    float rs = rs0 + rs1, q = q0 + q1;
    float rs_t = rs + __shfl_xor(rs, 32, 64);
    float q_t  = q  + __shfl_xor(q, 32, 64);
    float inv  = 1.f / rs_t;

    // broadcast inv to the C-layout rows this lane will store
    float invr[16];
#pragma unroll
    for (int reg = 0; reg < 16; ++reg) {
        int r = (reg & 3) + 8 * (reg >> 2) + 4 * hf;
        invr[reg] = __shfl(inv, r, 64);
    }

    // epilogue: normalize, store, accumulate loss terms.
    // n2-outer + plain cached stores is measured-best. Do not "fix" this again.
    float zs2 = 0.f;
    const size_t ob = (size_t)rowbase * DIM;
#pragma unroll
    for (int n2 = 0; n2 < 8; ++n2) {
#pragma unroll
        for (int reg = 0; reg < 16; ++reg) {
            int r = (reg & 3) + 8 * (reg >> 2) + 4 * hf;
            float v = o[n2][reg] * invr[reg];
            out[ob + (size_t)r * DIM + n2 * 32 + c31] = v;
            zs2 += v * v;
        }
    }

    // loss = mean(z^2) - 2*mean(zs.z) + mean(zs^2); zs.z per row = q_t * inv
    float lacc = sz2 + zs2;
    if (hf == 0) lacc -= 2.f * q_t * inv;
#pragma unroll
    for (int off = 32; off > 0; off >>= 1) lacc += __shfl_xor(lacc, off, 64);
    if (l == 0) atomicAdd(loss, lacc * (1.f / ((float)N_ROWS * (float)DIM)));
}

extern "C" void kernel_launch(void* const* d_in, const int* in_sizes, int n_in,
                              void* d_out, int out_size, void* d_ws, size_t ws_size,
                              hipStream_t stream) {
    const float* z = (const float*)d_in[0];
    const float* cb = (const float*)d_in[1];
    float* out = (float*)d_out;

    short* bg = (short*)d_ws;    // 32 chunks * 16384 shorts = 1 MB

    float* loss = out + (size_t)N_ROWS * DIM;
    hipMemsetAsync((void*)loss, 0, sizeof(float), stream);

    prep_kernel<<<dim3(NCHUNK), dim3(256), 0, stream>>>(cb, bg);
    svq_kernel<<<dim3(N_ROWS / BLK_ROWS), dim3(256), 0, stream>>>(
        z, bg, out, loss);
}

// Round 10
// 387.652 us; speedup vs baseline: 1.0707x; 1.0395x over previous
//
#include <hip/hip_runtime.h>
#include <hip/hip_bf16.h>

#define N_ROWS 131072
#define DIM 256
#define K_CODES 1024
#define BLK_ROWS 128        // 4 waves x 32 rows; 2 blocks/CU (load-bearing: r3/r4 regressions)
#define NCHUNK 32           // 32 codes per chunk
#define FRAG_SH 512         // shorts per fragment (64 lanes x 8 bf16)
#define CHUNK_SH (32 * FRAG_SH)   // 32 frags/chunk: [0..16)=GEMM1 A, [16..32)=GEMM2 B

typedef __attribute__((ext_vector_type(8))) short bf16x8;
typedef __attribute__((ext_vector_type(16))) float f32x16;

__device__ __forceinline__ short f2bf(float x) {
    unsigned u = __float_as_uint(x);
    u += 0x7fff + ((u >> 16) & 1);   // RNE
    return (short)(u >> 16);
}
// Session-locked lessons (each backed by a measured regression):
//  - manual f2bf, not asm cvt_pk: asm fences serialize phases (-11%; r5)
//  - 2 x 4-wave blocks/CU + per-chunk __syncthreads: cross-block wave overlap
//    carries the kernel (8-wave/counted-vmcnt -24% r3; chunk-rotation -32% r6)
//  - ALL MFMA operands via LDS (L2-direct A-frags: -85% r4 at the 256-reg cap)
//  - single 16-deep GEMM1 chain (dual 8-deep sA/sB: -6% r9)
//  - n2-outer cached stores (row-outer +65MB WRITE r1; nontemporal +68MB r3)

typedef const __attribute__((address_space(1))) unsigned int* gas1_t;
typedef __attribute__((address_space(3))) unsigned int* las3_t;
__device__ __forceinline__ void gload16(const short* g, short* l) {
    // per-lane global addr (contiguous 16B/lane); wave-uniform LDS base + lane*16
    __builtin_amdgcn_global_load_lds((gas1_t)(const void*)g, (las3_t)(void*)l, 16, 0, 0);
}

// ---------------- prep: codebook -> fragment-order bf16 (one block per 32-code chunk)
__global__ void prep_kernel(const float* __restrict__ cb,
                            short* __restrict__ bg) {
    __shared__ __align__(16) float tile[32 * 264];   // [code][d] fp32, stride 264
    __shared__ float en2s[32];
    const int tid = threadIdx.x;
    const int w = tid >> 6, l = tid & 63, hf = l >> 5, c31 = l & 31;
    const int ch = blockIdx.x, cb0 = ch * 32;

#pragma unroll
    for (int it = 0; it < 8; ++it) {
        int idx = it * 256 + tid;          // float4 index
        int r = idx >> 6, c = (idx & 63) * 4;
        *(float4*)&tile[r * 264 + c] = *(const float4*)&cb[(size_t)(cb0 + r) * DIM + c];
    }
    __syncthreads();

    {   // en2[c] = exp(-||e_c||^2), 8 threads per code
        int c = tid >> 3, part = tid & 7;
        float s = 0.f;
#pragma unroll
        for (int j = 0; j < 32; ++j) {
            float v = tile[c * 264 + part * 32 + j];
            s += v * v;
        }
        s += __shfl_xor(s, 1, 64);
        s += __shfl_xor(s, 2, 64);
        s += __shfl_xor(s, 4, 64);
        if (part == 0) en2s[c] = __expf(-s);
    }
    __syncthreads();

    // GEMM1 A-frags (f = t = 0..15): lane holds E[cb0 + c31][t*16 + hf*8 + j]
#pragma unroll
    for (int i = 0; i < 4; ++i) {
        int f = i * 4 + w;
        const float* src = &tile[c31 * 264 + f * 16 + hf * 8];
        float4 v0 = *(const float4*)src;
        float4 v1 = *(const float4*)(src + 4);
        bf16x8 v;
        v[0] = f2bf(v0.x); v[1] = f2bf(v0.y); v[2] = f2bf(v0.z); v[3] = f2bf(v0.w);
        v[4] = f2bf(v1.x); v[5] = f2bf(v1.y); v[6] = f2bf(v1.z); v[7] = f2bf(v1.w);
        *(bf16x8*)&bg[ch * CHUNK_SH + f * FRAG_SH + l * 8] = v;
    }
    // GEMM2 B-frags (f = 16 + n2*2 + t2), en2-folded, kappa code order:
    // slot (hf, j) holds code (t2*2 + (j>>2))*8 + 4*hf + (j&3), matching P's A-register order
#pragma unroll
    for (int i = 0; i < 4; ++i) {
        int g = i * 4 + w;
        int n2 = g >> 1, t2 = g & 1;
        int d = n2 * 32 + c31;
        bf16x8 v;
#pragma unroll
        for (int j = 0; j < 8; ++j) {
            int c2 = (t2 * 2 + (j >> 2)) * 8 + 4 * hf + (j & 3);
            v[j] = f2bf(tile[c2 * 264 + d] * en2s[c2]);
        }
        *(bf16x8*)&bg[ch * CHUNK_SH + (16 + g) * FRAG_SH + l * 8] = v;
    }
}

// ---------------- main fused kernel (round-2 measured optimum, restored) ----------------
__global__ __launch_bounds__(256, 2)
void svq_kernel(const float* __restrict__ z,
                const short* __restrict__ bg,
                float* __restrict__ out,
                float* __restrict__ loss) {
    __shared__ __align__(16) short lds_b[2 * CHUNK_SH];  // 2 x 32 KB double buffer

    const int tid = threadIdx.x;
    const int w = tid >> 6, l = tid & 63, hf = l >> 5, c31 = l & 31;
    const int rowbase = blockIdx.x * BLK_ROWS + w * 32;

    // z fragments: lane holds z[rowbase + c31][t*16 + hf*8 + j].
    // Same register layout serves as MFMA B-operand (B[k=d][n=row]) for GEMM1.
    bf16x8 za[16];
    float sz2 = 0.f;   // exact fp32 sum of z^2 over this lane's 128 elements
    {
        const float* zr = z + (size_t)(rowbase + c31) * DIM + hf * 8;
#pragma unroll
        for (int t = 0; t < 16; ++t) {
            float4 v0 = *(const float4*)(zr + t * 16);
            float4 v1 = *(const float4*)(zr + t * 16 + 4);
            sz2 += v0.x*v0.x + v0.y*v0.y + v0.z*v0.z + v0.w*v0.w
                 + v1.x*v1.x + v1.y*v1.y + v1.z*v1.z + v1.w*v1.w;
            bf16x8 a;
            a[0] = f2bf(v0.x); a[1] = f2bf(v0.y); a[2] = f2bf(v0.z); a[3] = f2bf(v0.w);
            a[4] = f2bf(v1.x); a[5] = f2bf(v1.y); a[6] = f2bf(v1.z); a[7] = f2bf(v1.w);
            za[t] = a;
        }
    }

    f32x16 o[8];
#pragma unroll
    for (int i = 0; i < 8; ++i)
        o[i] = (f32x16){0.f,0.f,0.f,0.f,0.f,0.f,0.f,0.f,0.f,0.f,0.f,0.f,0.f,0.f,0.f,0.f};
    float rs0 = 0.f, rs1 = 0.f;   // sum of p over this lane's codes (two partials)
    float q0 = 0.f,  q1 = 0.f;    // sum of p*s -> z_soft . z (two partials)

    // prologue: stage chunk 0 into buffer 0
    {
        const short* sg = bg + l * 8;
#pragma unroll
        for (int i = 0; i < 8; ++i) {
            int f = i * 4 + w;
            gload16(sg + f * FRAG_SH, &lds_b[f * FRAG_SH]);
        }
    }

    for (int ch = 0; ch < NCHUNK; ++ch) {
        // drains chunk-ch staging (which had all of compute(ch-1) to overlap)
        // and makes buffer (ch+1)&1 safe to overwrite
        __syncthreads();
        if (ch + 1 < NCHUNK) {
            const short* sg = bg + (ch + 1) * CHUNK_SH + l * 8;
            short* lbase = &lds_b[((ch + 1) & 1) * CHUNK_SH];
#pragma unroll
            for (int i = 0; i < 8; ++i) {
                int f = i * 4 + w;
                gload16(sg + f * FRAG_SH, lbase + f * FRAG_SH);
            }
        }

        const short* lb = &lds_b[(ch & 1) * CHUNK_SH + l * 8];

        // GEMM1 (transposed): S^T[32 codes x 32 rows] = E . Z^T
        f32x16 s = (f32x16){0.f,0.f,0.f,0.f,0.f,0.f,0.f,0.f,0.f,0.f,0.f,0.f,0.f,0.f,0.f,0.f};
#pragma unroll
        for (int t = 0; t < 16; ++t) {
            bf16x8 a = *(const bf16x8*)(lb + t * FRAG_SH);
            s = __builtin_amdgcn_mfma_f32_32x32x16_bf16(a, za[t], s, 0, 0, 0);
        }

        // softmax half 1 (regs 0..7 -> a20), then ISSUE its 8 GEMM2 MFMAs
        // immediately so they drain in the matrix pipe while the wave computes
        // half 2 on the VALU (MFMA issue is non-blocking for the wave).
        bf16x8 a20;
#pragma unroll
        for (int reg = 0; reg < 8; ++reg) {
            float sv = s[reg];
            float p = exp2f(sv * 2.8853900818f);   // exp(2 z.e)
            if (reg & 1) { rs1 += p; q1 += p * sv; }
            else         { rs0 += p; q0 += p * sv; }
            a20[reg] = f2bf(p);
        }
#pragma unroll
        for (int n2 = 0; n2 < 8; ++n2) {
            bf16x8 b0 = *(const bf16x8*)(lb + (16 + n2 * 2) * FRAG_SH);
            o[n2] = __builtin_amdgcn_mfma_f32_32x32x16_bf16(a20, b0, o[n2], 0, 0, 0);
        }

        // softmax half 2 (regs 8..15 -> a21), then its 8 GEMM2 MFMAs
        bf16x8 a21;
#pragma unroll
        for (int reg = 8; reg < 16; ++reg) {
            float sv = s[reg];
            float p = exp2f(sv * 2.8853900818f);
            if (reg & 1) { rs1 += p; q1 += p * sv; }
            else         { rs0 += p; q0 += p * sv; }
            a21[reg - 8] = f2bf(p);
        }
#pragma unroll
        for (int n2 = 0; n2 < 8; ++n2) {
            bf16x8 b1 = *(const bf16x8*)(lb + (16 + n2 * 2 + 1) * FRAG_SH);
            o[n2] = __builtin_amdgcn_mfma_f32_32x32x16_bf16(a21, b1, o[n2], 0, 0, 0);
        }
    }

    // combine the two half-dim/half-code lanes of each row
    float rs = rs0 + rs1, q = q0 + q1;
    float rs_t = rs + __shfl_xor(rs, 32, 64);
    float q_t  = q  + __shfl_xor(q, 32, 64);
    float inv  = 1.f / rs_t;

    // broadcast inv to the C-layout rows this lane will store
    float invr[16];
#pragma unroll
    for (int reg = 0; reg < 16; ++reg) {
        int r = (reg & 3) + 8 * (reg >> 2) + 4 * hf;
        invr[reg] = __shfl(inv, r, 64);
    }

    // epilogue: normalize, store, accumulate loss terms.
    // n2-outer + plain cached stores is measured-best. Do not "fix" this again.
    float zs2 = 0.f;
    const size_t ob = (size_t)rowbase * DIM;
#pragma unroll
    for (int n2 = 0; n2 < 8; ++n2) {
#pragma unroll
        for (int reg = 0; reg < 16; ++reg) {
            int r = (reg & 3) + 8 * (reg >> 2) + 4 * hf;
            float v = o[n2][reg] * invr[reg];
            out[ob + (size_t)r * DIM + n2 * 32 + c31] = v;
            zs2 += v * v;
        }
    }

    // loss = mean(z^2) - 2*mean(zs.z) + mean(zs^2); zs.z per row = q_t * inv
    float lacc = sz2 + zs2;
    if (hf == 0) lacc -= 2.f * q_t * inv;
#pragma unroll
    for (int off = 32; off > 0; off >>= 1) lacc += __shfl_xor(lacc, off, 64);
    if (l == 0) atomicAdd(loss, lacc * (1.f / ((float)N_ROWS * (float)DIM)));
}

extern "C" void kernel_launch(void* const* d_in, const int* in_sizes, int n_in,
                              void* d_out, int out_size, void* d_ws, size_t ws_size,
                              hipStream_t stream) {
    const float* z = (const float*)d_in[0];
    const float* cb = (const float*)d_in[1];
    float* out = (float*)d_out;

    short* bg = (short*)d_ws;    // 32 chunks * 16384 shorts = 1 MB

    float* loss = out + (size_t)N_ROWS * DIM;
    hipMemsetAsync((void*)loss, 0, sizeof(float), stream);

    prep_kernel<<<dim3(NCHUNK), dim3(256), 0, stream>>>(cb, bg);
    svq_kernel<<<dim3(N_ROWS / BLK_ROWS), dim3(256), 0, stream>>>(
        z, bg, out, loss);
}